// Round 15
// baseline (271.001 us; speedup 1.0000x reference)
//
#include <hip/hip_runtime.h>

#define NUM_K 64
#define CDIM 32
#define HW 16384          // 128*128
#define NPTS 1048576      // 64*128*128
#define NELEMD 33554432.0 // 64*32*128*128
#define BOUND 4e-4f       // > 2x worst-case |screen - numpy| distance error

typedef short short8 __attribute__((ext_vector_type(8)));
typedef float f4 __attribute__((ext_vector_type(4)));
typedef unsigned int uint4v __attribute__((ext_vector_type(4)));

// RN-even fp32 -> bf16 (bit trick; matches __float2bfloat16, no NaN here)
__device__ __forceinline__ unsigned short rnbf16(float v) {
    unsigned u = __builtin_bit_cast(unsigned, v);
    unsigned r = u + 0x7FFFu + ((u >> 16) & 1u);
    return (unsigned short)(r >> 16);
}
__device__ __forceinline__ float frombf(unsigned short h) {
    unsigned u = ((unsigned)h) << 16;
    return __builtin_bit_cast(float, u);
}

// Block = 128 points = 4 waves x 32 pts (2 M-tiles of 16). MFMA bf16 hi/lo
// screen (3 passes) + certified exact numpy refine on near-ties.
__global__ __launch_bounds__(256) void vq_main(const float* __restrict__ x,
                                               const float* __restrict__ emb,
                                               float* __restrict__ outq,
                                               double* __restrict__ ws) {
#pragma clang fp contract(off)
    __shared__ __align__(16) unsigned short sAh[8 * 512]; // [wmt][g][p16][i]
    __shared__ __align__(16) unsigned short sAl[8 * 512];
    __shared__ __align__(16) unsigned short sBh[2048];    // [nt][g][n16][i]
    __shared__ __align__(16) unsigned short sBl[2048];
    __shared__ float sErow[64 * 33];  // exact fp32 codebook, row-padded
    __shared__ float sD[4 * 16 * 68]; // per-wave screen tile [pt][k], padded
    __shared__ float sAx[128];        // exact numpy-tree ||x||^2 per point
    __shared__ float sBg[64];         // exact numpy-tree ||e_k||^2
    __shared__ int   sBiW[4][16];
    __shared__ float sRed[4];

    const int t = threadIdx.x;
    const int p0 = blockIdx.x * 128;  // 128 | 16384 -> one image per block
    const int bimg = p0 >> 14;
    const size_t gbase = (size_t)bimg * (CDIM * HW) + (p0 & (HW - 1));

    if (t < 128) {                    // x stager: thread <-> point
        const int wmt = t >> 4, p16 = t & 15;
        float r8[8];
        #pragma unroll
        for (int g = 0; g < 4; ++g) {
            unsigned hb[4], lb[4];
            #pragma unroll
            for (int ii = 0; ii < 8; ++ii) {
                const int c = g * 8 + ii;
                float xc = x[gbase + (size_t)c * HW + t];   // coalesced
                float pp = xc * xc;                          // rounds (contract off)
                if (g == 0) r8[ii] = pp; else r8[ii] = r8[ii] + pp; // numpy tree partials
                unsigned short h = rnbf16(xc);
                unsigned short lo = rnbf16(xc - frombf(h));  // xc-h exact (Sterbenz)
                if ((ii & 1) == 0) { hb[ii >> 1] = h; lb[ii >> 1] = lo; }
                else { hb[ii >> 1] |= ((unsigned)h) << 16; lb[ii >> 1] |= ((unsigned)lo) << 16; }
            }
            *(uint4v*)&sAh[wmt * 512 + g * 128 + p16 * 8] = (uint4v){hb[0], hb[1], hb[2], hb[3]};
            *(uint4v*)&sAl[wmt * 512 + g * 128 + p16 * 8] = (uint4v){lb[0], lb[1], lb[2], lb[3]};
        }
        sAx[t] = ((r8[0] + r8[1]) + (r8[2] + r8[3])) + ((r8[4] + r8[5]) + (r8[6] + r8[7]));
    } else if (t < 192) {             // emb stager: thread <-> code k
        const int k = t - 128;
        const int nt = k >> 4, n16 = k & 15;
        float r8[8];
        #pragma unroll
        for (int g = 0; g < 4; ++g) {
            unsigned hb[4], lb[4];
            #pragma unroll
            for (int ii = 0; ii < 8; ++ii) {
                const int c = g * 8 + ii;
                float e = emb[k * CDIM + c];
                sErow[k * 33 + c] = e;
                float pp = e * e;
                if (g == 0) r8[ii] = pp; else r8[ii] = r8[ii] + pp;
                unsigned short h = rnbf16(e);
                unsigned short lo = rnbf16(e - frombf(h));
                if ((ii & 1) == 0) { hb[ii >> 1] = h; lb[ii >> 1] = lo; }
                else { hb[ii >> 1] |= ((unsigned)h) << 16; lb[ii >> 1] |= ((unsigned)lo) << 16; }
            }
            *(uint4v*)&sBh[((nt * 4 + g) * 16 + n16) * 8] = (uint4v){hb[0], hb[1], hb[2], hb[3]};
            *(uint4v*)&sBl[((nt * 4 + g) * 16 + n16) * 8] = (uint4v){lb[0], lb[1], lb[2], lb[3]};
        }
        sBg[k] = ((r8[0] + r8[1]) + (r8[2] + r8[3])) + ((r8[4] + r8[5]) + (r8[6] + r8[7]));
    }
    __syncthreads();   // the only block-wide barrier before the final reduce

    const int w = t >> 6, l = t & 63;
    const int g = l >> 4, n16 = l & 15;

    short8 bh[4], bl[4];              // hoisted B fragments (k-layout consistent
    #pragma unroll                    // with A: dot is k-permutation-invariant)
    for (int nt = 0; nt < 4; ++nt) {
        bh[nt] = *(const short8*)&sBh[((nt * 4 + g) * 16 + n16) * 8];
        bl[nt] = *(const short8*)&sBl[((nt * 4 + g) * 16 + n16) * 8];
    }

    float lsum = 0.f;
    #pragma unroll
    for (int mt = 0; mt < 2; ++mt) {
        const int wmt = w * 2 + mt;
        short8 ah = *(const short8*)&sAh[wmt * 512 + g * 128 + n16 * 8];
        short8 al = *(const short8*)&sAl[wmt * 512 + g * 128 + n16 * 8];
        #pragma unroll
        for (int nt = 0; nt < 4; ++nt) {
            f4 acc = (f4){0.f, 0.f, 0.f, 0.f};
            acc = __builtin_amdgcn_mfma_f32_16x16x32_bf16(ah, bh[nt], acc, 0, 0, 0);
            acc = __builtin_amdgcn_mfma_f32_16x16x32_bf16(ah, bl[nt], acc, 0, 0, 0);
            acc = __builtin_amdgcn_mfma_f32_16x16x32_bf16(al, bh[nt], acc, 0, 0, 0);
            #pragma unroll
            for (int r = 0; r < 4; ++r) {          // C/D: col=lane&15, row=(lane>>4)*4+r
                int m = g * 4 + r;
                int k = nt * 16 + n16;
                sD[(w * 16 + m) * 68 + k] = fmaf(-2.f, acc[r], sBg[k]); // screen s_k
            }
        }
        asm volatile("s_waitcnt lgkmcnt(0)" ::: "memory");  // sD wave-private: no barrier

        // quarter scan: lane (n16,g) scans pt=n16, k in [16g,16g+16), first-min
        float best = 3.4028235e38f, second = 3.4028235e38f;
        int bi = 0;
        const float* row = &sD[(w * 16 + n16) * 68];
        #pragma unroll
        for (int j = 0; j < 16; ++j) {
            int k = g * 16 + j;
            float s = row[k];
            if (s < best) { second = best; best = s; bi = k; }
            else if (s < second) second = s;
        }
        #pragma unroll
        for (int step = 0; step < 2; ++step) {     // merge quarters; lower-k wins ties
            int mask = 16 << step;
            float ob = __shfl_xor(best, mask, 64);
            float os = __shfl_xor(second, mask, 64);
            int   obi = __shfl_xor(bi, mask, 64);
            bool mineLower = ((l & mask) == 0);
            float ab = mineLower ? best : ob,  bb = mineLower ? ob : best;
            float as_ = mineLower ? second : os, bs = mineLower ? os : second;
            int   abi = mineLower ? bi : obi,  bbi = mineLower ? obi : bi;
            if (bb < ab) { best = bb; bi = bbi; second = fminf(ab, fminf(as_, bs)); }
            else         { best = ab; bi = abi; second = fminf(bb, fminf(as_, bs)); }
        }

        float lp = 0.f;
        if (l < 16) {                 // owner lane l = point l of this M-tile
            const int ptb = w * 32 + mt * 16 + l;
            const float A = sAx[ptb];
            if (second - best < BOUND) {
                // certified refine: exact numpy d for all k within BOUND (incl. winner)
                float bd = 3.4028235e38f; int bk = 0;
                for (int k2 = 0; k2 < 64; ++k2) {
                    float s = sD[(w * 16 + l) * 68 + k2];
                    if (s <= best + BOUND) {
                        const volatile float* xv = x;   // block load hoist to hot path
                        float acc = 0.f;
                        #pragma unroll
                        for (int c = 0; c < CDIM; ++c)  // exact ascending-c fma chain
                            acc = fmaf(xv[gbase + (size_t)c * HW + ptb], sErow[k2 * 33 + c], acc);
                        float t1 = A + sBg[k2];
                        float d = fmaf(-2.f, acc, t1);  // == fl(fl(A+B)-2C) bitwise
                        if (d < bd) { bd = d; bk = k2; }
                    }
                }
                bi = bk; lp = bd;
            } else {
                lp = A + best;        // loss only: +-1e-4 vs exact, threshold 2%
            }
            sBiW[w][l] = bi;
        }
        asm volatile("s_waitcnt lgkmcnt(0)" ::: "memory");

        const int mybi = sBiW[w][n16];
        const int ptb2 = w * 32 + mt * 16 + n16;
        #pragma unroll
        for (int j = 0; j < 8; ++j) { // lane (n16,g) stores channels c = g+4j
            int c = g + 4 * j;
            outq[gbase + (size_t)c * HW + ptb2] = sErow[mybi * 33 + c];
        }
        lsum += lp;
    }

    #pragma unroll
    for (int off = 1; off < 64; off <<= 1)
        lsum += __shfl_xor(lsum, off, 64);
    if (l == 0) sRed[w] = lsum;
    __syncthreads();
    if (t == 0)
        atomicAdd(ws, (double)(sRed[0] + sRed[1] + sRed[2] + sRed[3]));
}

__global__ void vq_finish(const double* __restrict__ ws, float* __restrict__ loss) {
    loss[0] = (float)(1.25 * ws[0] / NELEMD);
}

extern "C" void kernel_launch(void* const* d_in, const int* in_sizes, int n_in,
                              void* d_out, int out_size, void* d_ws, size_t ws_size,
                              hipStream_t stream) {
    const float* x = (const float*)d_in[0];
    const float* emb = (const float*)d_in[1];
    float* out = (float*)d_out;
    double* acc = (double*)d_ws;

    hipMemsetAsync(d_ws, 0, sizeof(double), stream);  // zero loss accumulator every call
    vq_main<<<NPTS / 128, 256, 0, stream>>>(x, emb, out + 1, acc);
    vq_finish<<<1, 1, 0, stream>>>(acc, out);
}

// Round 16
// 86.044 us; speedup vs baseline: 3.1496x; 3.1496x over previous
//
#include <hip/hip_runtime.h>

#define NUM_K 64
#define CDIM 32
#define HW 16384          // 128*128
#define NPTS 1048576      // 64*128*128
#define NELEMD 33554432.0 // 64*32*128*128

typedef float v2f __attribute__((ext_vector_type(2)));

// numpy pairwise sum of squares, n=32 contiguous: 8 accumulators + fixed tree.
__device__ __forceinline__ float np_sumsq32(const float* v) {
#pragma clang fp contract(off)
    float r[8];
    #pragma unroll
    for (int j = 0; j < 8; ++j) {
        float p0 = v[j] * v[j];
        float p1 = v[j + 8] * v[j + 8];
        float p2 = v[j + 16] * v[j + 16];
        float p3 = v[j + 24] * v[j + 24];
        r[j] = ((p0 + p1) + p2) + p3;
    }
    return ((r[0] + r[1]) + (r[2] + r[3])) + ((r[4] + r[5]) + (r[6] + r[7]));
}

// Prep: B[k] = np.sum(emb*emb,axis=1) (numpy fp32 order) and embT[c][k]
// (transposed codebook, contiguous in k) -> global scratch.
__global__ void vq_prep(const float* __restrict__ emb, float* __restrict__ Bg,
                        float* __restrict__ embT) {
#pragma clang fp contract(off)
    int k = threadIdx.x;
    if (k < NUM_K) {
        float e[CDIM];
        #pragma unroll
        for (int c = 0; c < CDIM; ++c) e[c] = emb[k * CDIM + c];
        Bg[k] = np_sumsq32(e);
        #pragma unroll
        for (int c = 0; c < CDIM; ++c) embT[c * NUM_K + k] = e[c];
    }
}

// Loop-interchanged main (c outer, k inner) + 2-stage software pipeline.
// Session's measured optimum (R10: 84.8 us). Falsified alternatives:
// k-outer serial chains (R3-R8: remat/AGPR-parking pathology), occupancy
// boosts via k-splits (R11/R12/R14: spill or slower), MFMA screen (R15: 3x).
__global__ __launch_bounds__(256) void vq_main(const float* __restrict__ x,
                                               const float* __restrict__ embT,
                                               const float* __restrict__ Bg,
                                               float* __restrict__ outq,
                                               double* __restrict__ ws) {
#pragma clang fp contract(off)
    __shared__ float sET[CDIM][NUM_K];  // gather table (same layout as embT)
    __shared__ float sRed[4];

    const int t = threadIdx.x;
    #pragma unroll
    for (int i = t; i < NUM_K * CDIM; i += 256)
        ((float*)sET)[i] = embT[i];     // coalesced read, conflict-free write
    __syncthreads();

    const int p = blockIdx.x * 256 + t;
    const int b = p >> 14;
    const size_t base = (size_t)b * (CDIM * HW) + (p & (HW - 1));
    const float* xp = x + base;

    v2f acc2[CDIM];                     // acc2[q] = {C_{2q}, C_{2q+1}}
    #pragma unroll
    for (int q = 0; q < CDIM; ++q) acc2[q] = (v2f){0.f, 0.f};
    float r[8];                         // numpy pairwise-tree partials for A

    float cur[8], nxt[8];
    #pragma unroll
    for (int j = 0; j < 8; ++j)
        cur[j] = xp[(size_t)j * HW];    // prologue: group 0 loads

    #pragma unroll
    for (int g = 0; g < 4; ++g) {
        if (g < 3) {                    // issue next group's loads FIRST
            #pragma unroll
            for (int j = 0; j < 8; ++j)
                nxt[j] = xp[(size_t)((g + 1) * 8 + j) * HW];
        }
        #pragma unroll
        for (int j = 0; j < 8; ++j) {
            const int c = g * 8 + j;
            const float xc = cur[j];
            const float pp = xc * xc;               // rounds individually
            // r_j = ((p_j + p_{j+8}) + p_{j+16}) + p_{j+24}  == numpy tree
            if (g == 0) r[j] = pp; else r[j] = r[j] + pp;
            const v2f xx = (v2f){xc, xc};
            const v2f* __restrict__ e2 = (const v2f*)(embT + c * NUM_K); // uniform row
            #pragma unroll
            for (int q = 0; q < CDIM; ++q)
                acc2[q] = __builtin_elementwise_fma(xx, e2[q], acc2[q]); // per-elem fma
        }
        if (g < 3) {
            #pragma unroll
            for (int j = 0; j < 8; ++j) cur[j] = nxt[j];   // register rotate
        }
    }
    const float A = ((r[0] + r[1]) + (r[2] + r[3])) + ((r[4] + r[5]) + (r[6] + r[7]));

    // d_k = fp32( fp32(A + B_k) - 2*C_k ) == fmaf(-2, C_k, A+B_k) bitwise.
    // Ascending k, strict <  => first-min (np.argmin). Each C_k saw the exact
    // ascending-c fp32 fma chain of the passing R3/R4/R9 kernels.
    float best = 3.4028235e38f;
    int bi = 0;
    #pragma unroll
    for (int q = 0; q < CDIM; ++q) {
        float d0 = fmaf(-2.f, acc2[q].x, A + Bg[2 * q]);
        float d1 = fmaf(-2.f, acc2[q].y, A + Bg[2 * q + 1]);
        if (d0 < best) { best = d0; bi = 2 * q; }
        if (d1 < best) { best = d1; bi = 2 * q + 1; }
    }

    // Winner gather + coalesced stores. Loss contribution == best (validated R9).
    float* op = outq + base;
    #pragma unroll
    for (int c = 0; c < CDIM; ++c)
        op[(size_t)c * HW] = sET[c][bi];   // bank=bi%32 gather: ~free

    float lsum = best;
    #pragma unroll
    for (int off = 32; off > 0; off >>= 1)
        lsum += __shfl_down(lsum, off, 64);
    const int wid = t >> 6;
    if ((t & 63) == 0) sRed[wid] = lsum;
    __syncthreads();
    if (t == 0) {
        double bs = (double)sRed[0] + (double)sRed[1] + (double)sRed[2] + (double)sRed[3];
        atomicAdd(ws, bs);
    }
}

__global__ void vq_finish(const double* __restrict__ ws, float* __restrict__ loss) {
    loss[0] = (float)(1.25 * ws[0] / NELEMD);
}

extern "C" void kernel_launch(void* const* d_in, const int* in_sizes, int n_in,
                              void* d_out, int out_size, void* d_ws, size_t ws_size,
                              hipStream_t stream) {
    const float* x = (const float*)d_in[0];
    const float* emb = (const float*)d_in[1];
    float* out = (float*)d_out;
    // ws layout: [0,8) double loss acc; [64,320) Bg[64]; [320,8512) embT[32][64]
    double* acc = (double*)d_ws;
    float* Bg = (float*)((char*)d_ws + 64);
    float* embT = (float*)((char*)d_ws + 320);

    hipMemsetAsync(d_ws, 0, sizeof(double), stream);
    vq_prep<<<1, 64, 0, stream>>>(emb, Bg, embT);
    vq_main<<<NPTS / 256, 256, 0, stream>>>(x, embT, Bg, out + 1, acc);
    vq_finish<<<1, 1, 0, stream>>>(acc, out);
}